// Round 5
// baseline (100.191 us; speedup 1.0000x reference)
//
#include <hip/hip_runtime.h>
#include <hip/hip_bf16.h>
#include <stdint.h>

#define N_TOKENS    16384
#define MODEL_DIM   2048
#define NUM_EXPERTS 16
#define CAPACITY    2048
#define NBLK        256    // token blocks of 64
// d_out is FLOAT32. Element layout: [0]=l_aux, [1..32769)=weights[N][2],
// [32769..65537)=indices[E*CAP], [65537..98305)=expert_ids[E*CAP]
#define W_OFF       1
#define IDX_OFF     (1 + 2 * N_TOKENS)                  // 32769
#define EID_OFF     (IDX_OFF + NUM_EXPERTS * CAPACITY)  // 65537

// Scratch inside d_out's expert_ids region (131 KB available, 49 KB used);
// clobbered only by the FINAL kernel k_eid. Same-stream serialization.
#define SCR_BYTE  (4 * EID_OFF)
#define SC_E01    0        // uint8  [16384]: e1 | (e2<<4)
#define SC_CNT    16384    // uint16 [16][256]
#define SC_START  24576    // uint16 [16][256]
#define SC_ME     32768    // float  [256][16]
#define SC_CE     49152    // int    [16]

// ============ K1: fused GEMV + softmax + top2 + counts + me ============
// 256 blocks x 1024 thr (16 waves = 4/SIMD). Block b: tokens [b*64, b*64+64).
// Wave q owns dims [q*128, q*128+128). lane = token. Weights are wave-uniform
// (scalar-pipe loads, no LDS); LDS only holds partial logits (stride-5 float4
// rows -> 8-way bank spread = LDS data-bus floor).
__global__ __launch_bounds__(1024) void k_gate(
    const float* __restrict__ x, const float* __restrict__ wg,
    float* __restrict__ out, uint8_t* __restrict__ scr)
{
  __shared__ float4 pred[16 * 64 * 5];   // 80 KB
  const int tid = threadIdx.x;
  const int b = blockIdx.x;
  const int l = tid & 63;
  const int q = __builtin_amdgcn_readfirstlane(tid >> 6);   // uniform -> SGPR
  const int t = b * 64 + l;

  const float4* xq = reinterpret_cast<const float4*>(x + (size_t)t * MODEL_DIM + q * 128);
  const float*  wq = wg + q * 128;       // uniform base

  float acc[NUM_EXPERTS];
#pragma unroll
  for (int e = 0; e < NUM_EXPERTS; e++) acc[e] = 0.f;

#pragma unroll 4
  for (int j = 0; j < 32; j++) {
    float4 xv = xq[j];                   // per-lane (token row)
#pragma unroll
    for (int e = 0; e < NUM_EXPERTS; e++) {
      // wave-uniform address -> scalar load path
      float4 w = *reinterpret_cast<const float4*>(wq + e * MODEL_DIM + j * 4);
      acc[e] += xv.x * w.x + xv.y * w.y + xv.z * w.z + xv.w * w.w;
    }
  }

#pragma unroll
  for (int e4 = 0; e4 < 4; e4++)
    pred[(q * 64 + l) * 5 + e4] =
        make_float4(acc[e4 * 4], acc[e4 * 4 + 1], acc[e4 * 4 + 2], acc[e4 * 4 + 3]);
  __syncthreads();

  if (tid < 64) {   // wave 0 finishes the block's 64 tokens
    float logit[NUM_EXPERTS];
#pragma unroll
    for (int e = 0; e < NUM_EXPERTS; e++) logit[e] = 0.f;
    for (int qq = 0; qq < 16; qq++) {
#pragma unroll
      for (int e4 = 0; e4 < 4; e4++) {
        float4 v = pred[(qq * 64 + l) * 5 + e4];
        logit[e4 * 4 + 0] += v.x; logit[e4 * 4 + 1] += v.y;
        logit[e4 * 4 + 2] += v.z; logit[e4 * 4 + 3] += v.w;
      }
    }
    float m = logit[0];
#pragma unroll
    for (int e = 1; e < NUM_EXPERTS; e++) m = fmaxf(m, logit[e]);
    float g[NUM_EXPERTS]; float z = 0.f;
#pragma unroll
    for (int e = 0; e < NUM_EXPERTS; e++) { g[e] = expf(logit[e] - m); z += g[e]; }
    float inv = 1.f / z;
#pragma unroll
    for (int e = 0; e < NUM_EXPERTS; e++) g[e] *= inv;

    // top-2, ties -> lower index (matches lax.top_k / argmax)
    float v1 = g[0], v2 = -1.f; int e1 = 0, e2 = 0;
#pragma unroll
    for (int e = 1; e < NUM_EXPERTS; e++) {
      if (g[e] > v1) { v2 = v1; e2 = e1; v1 = g[e]; e1 = e; }
      else if (g[e] > v2) { v2 = g[e]; e2 = e; }
    }
    out[W_OFF + 2 * t]     = v1;
    out[W_OFF + 2 * t + 1] = v2;
    scr[SC_E01 + t] = (uint8_t)(e1 | (e2 << 4));

    // per-block routed counts (token order preserved) + argmax count
    int mycount = 0, myce = 0;
    for (int e = 0; e < NUM_EXPERTS; e++) {
      unsigned long long m1 = __ballot(e1 == e);
      unsigned long long m2 = __ballot(e2 == e);
      if (l == e) { mycount = __popcll(m1 | m2); myce = __popcll(m1); }
    }
    if (l < NUM_EXPERTS) {
      reinterpret_cast<uint16_t*>(scr + SC_CNT)[l * NBLK + b] = (uint16_t)mycount;
      atomicAdd(reinterpret_cast<int*>(scr + SC_CE) + l, myce);
    }

    // me partial: butterfly over the 64 tokens
#pragma unroll
    for (int e = 0; e < NUM_EXPERTS; e++) {
#pragma unroll
      for (int off = 1; off < 64; off <<= 1) g[e] += __shfl_xor(g[e], off, 64);
    }
    if (l == 0) {
      float* mp = reinterpret_cast<float*>(scr + SC_ME);
#pragma unroll
      for (int e = 0; e < NUM_EXPERTS; e++) mp[b * NUM_EXPERTS + e] = g[e];
    }
  }
}

// ============ K2: per-expert exclusive prefix over 256 blocks ============
__global__ __launch_bounds__(256) void k_prefix(uint8_t* __restrict__ scr) {
  const uint16_t* counts = reinterpret_cast<const uint16_t*>(scr + SC_CNT);
  uint16_t* starts = reinterpret_cast<uint16_t*>(scr + SC_START);
  __shared__ int gs[NUM_EXPERTS][16];
  __shared__ int gstart[NUM_EXPERTS][17];
  const int tid = threadIdx.x;
  const int e = tid >> 4, grp = tid & 15;
  int s = 0;
  for (int c = grp * 16; c < grp * 16 + 16; c++) s += counts[e * NBLK + c];
  gs[e][grp] = s;
  __syncthreads();
  if (tid < NUM_EXPERTS) {
    int run = 0;
    for (int g2 = 0; g2 < 16; g2++) { gstart[tid][g2] = run; run += gs[tid][g2]; }
  }
  __syncthreads();
  int run = gstart[e][grp];
  for (int c = grp * 16; c < grp * 16 + 16; c++) {
    starts[e * NBLK + c] = (uint16_t)run;
    run += counts[e * NBLK + c];
  }
}

// ============ K3: l_aux ============
__global__ __launch_bounds__(64) void k_laux(
    const uint8_t* __restrict__ scr, float* __restrict__ out) {
  const float* mepart = reinterpret_cast<const float*>(scr + SC_ME);
  const int* cecnt = reinterpret_cast<const int*>(scr + SC_CE);
  const int lane = threadIdx.x;
  float prod = 0.f;
  if (lane < NUM_EXPERTS) {
    float s = 0.f;
    for (int b = 0; b < NBLK; b++) s += mepart[b * NUM_EXPERTS + lane];
    float me = s * (1.0f / N_TOKENS);
    float ce = (float)cecnt[lane] * (1.0f / N_TOKENS);
    prod = me * ce;
  }
#pragma unroll
  for (int off = 32; off > 0; off >>= 1) prod += __shfl_xor(prod, off, 64);
  if (lane == 0) out[0] = prod * (float)NUM_EXPERTS;
}

// ============ K4: scatter token ids into capacity table ============
__global__ __launch_bounds__(64) void k_scatter(
    const uint8_t* __restrict__ scr, float* __restrict__ out) {
  const uint16_t* starts = reinterpret_cast<const uint16_t*>(scr + SC_START);
  const int c = blockIdx.x;
  const int lane = threadIdx.x;
  const int t = c * 64 + lane;
  const int v = scr[SC_E01 + t];
  const int e1 = v & 15, e2 = v >> 4;
  const unsigned long long below = (1ull << lane) - 1ull;
  int p1 = CAPACITY, p2 = CAPACITY;
  for (int e = 0; e < NUM_EXPERTS; e++) {
    unsigned long long m = __ballot(e1 == e) | __ballot(e2 == e);
    int r = __popcll(m & below);
    int sbase = (int)starts[e * NBLK + c];
    if (e1 == e) p1 = sbase + r;
    if (e2 == e) p2 = sbase + r;
  }
  float tf = (float)t;   // exact in fp32
  if ((unsigned)p1 < (unsigned)CAPACITY) out[IDX_OFF + e1 * CAPACITY + p1] = tf;
  if ((unsigned)p2 < (unsigned)CAPACITY) out[IDX_OFF + e2 * CAPACITY + p2] = tf;
}

// ============ K5: fill -1 in empty index slots ============
__global__ __launch_bounds__(256) void k_fill_idx(
    const uint8_t* __restrict__ scr, float* __restrict__ out) {
  const uint16_t* counts = reinterpret_cast<const uint16_t*>(scr + SC_CNT);
  const uint16_t* starts = reinterpret_cast<const uint16_t*>(scr + SC_START);
  const int i = blockIdx.x * 256 + threadIdx.x;   // 0..32767
  const int e = i >> 11;
  const int p = i & (CAPACITY - 1);
  const int tot = (int)starts[e * NBLK + NBLK - 1] + (int)counts[e * NBLK + NBLK - 1];
  if (p >= tot) out[IDX_OFF + i] = -1.0f;
}

// ============ K6 (LAST — clobbers scratch): expert_ids ============
__global__ __launch_bounds__(256) void k_eid(float* __restrict__ out) {
  const int i = blockIdx.x * 256 + threadIdx.x;   // 0..32767
  out[EID_OFF + i] = (float)(i >> 11);
}

extern "C" void kernel_launch(void* const* d_in, const int* in_sizes, int n_in,
                              void* d_out, int out_size, void* d_ws, size_t ws_size,
                              hipStream_t stream) {
  const float* x  = (const float*)d_in[0];
  const float* wg = (const float*)d_in[1];
  float* out = (float*)d_out;
  uint8_t* scr = (uint8_t*)d_out + SCR_BYTE;
  (void)d_ws; (void)ws_size;

  hipMemsetAsync(scr + SC_CE, 0, NUM_EXPERTS * sizeof(int), stream);
  k_gate<<<NBLK, 1024, 0, stream>>>(x, wg, out, scr);
  k_prefix<<<1, 256, 0, stream>>>(scr);
  k_laux<<<1, 64, 0, stream>>>(scr, out);
  k_scatter<<<NBLK, 64, 0, stream>>>(scr, out);
  k_fill_idx<<<128, 256, 0, stream>>>(scr, out);
  k_eid<<<128, 256, 0, stream>>>(out);
}

// Round 6
// 76.080 us; speedup vs baseline: 1.3169x; 1.3169x over previous
//
#include <hip/hip_runtime.h>
#include <hip/hip_bf16.h>
#include <stdint.h>

#define N_TOKENS    16384
#define MODEL_DIM   2048
#define NUM_EXPERTS 16
#define CAPACITY    2048
#define NBLK        256    // token blocks of 64
// d_out is FLOAT32. Element layout: [0]=l_aux, [1..32769)=weights[N][2],
// [32769..65537)=indices[E*CAP], [65537..98305)=expert_ids[E*CAP]
#define W_OFF       1
#define IDX_OFF     (1 + 2 * N_TOKENS)                  // 32769
#define EID_OFF     (IDX_OFF + NUM_EXPERTS * CAPACITY)  // 65537

// Scratch inside d_out's expert_ids region (131 KB available, 49 KB used);
// clobbered only by the FINAL kernel k_eid. Same-stream serialization.
#define SCR_BYTE  (4 * EID_OFF)
#define SC_E01    0        // uint8  [16384]: e1 | (e2<<4)
#define SC_CNT    16384    // uint16 [16][256]
#define SC_START  24576    // uint16 [16][256]
#define SC_ME     32768    // float  [256][16]
#define SC_CE     49152    // int    [16]

// DPP-based add of partner lane's value (compile-time ctrl).
// xor1 = quad_perm[1,0,3,2]=0xB1; xor2 = quad_perm[2,3,0,1]=0x4E;
// xor7 = ROW_HALF_MIRROR=0x141; xor15 = ROW_MIRROR=0x140.
#define DPP_ADD(v, ctrl)                                                      \
  (v) += __int_as_float(__builtin_amdgcn_update_dpp(                          \
      0, __float_as_int(v), (ctrl), 0xF, 0xF, true))

__device__ __forceinline__ float dot4(float4 a, float4 b) {
  return a.x * b.x + a.y * b.y + a.z * b.z + a.w * b.w;
}

// ============ K1: fused GEMV + softmax + top2 + counts + me ============
// 256 blocks x 512 thr (8 waves, 2/SIMD). Block b: tokens [b*64, b*64+64).
// Wave wv owns tokens tok0..tok0+7 (T=8). Lane l owns k-offsets
// {j*256 + l*4 + 0..3}: x loads are 1KB-contiguous (perfectly coalesced,
// read once); w fragments are coalesced global loads reused across 8 tokens
// and 8 waves (L1-hot). NO LDS in the main loop. k-reduction: 4 DPP
// butterfly steps (intra-16), group partials via 16.5KB LDS, final sum of 4.
__global__ __launch_bounds__(512, 2) void k_gate(
    const float* __restrict__ x, const float* __restrict__ wg,
    float* __restrict__ out, uint8_t* __restrict__ scr)
{
  __shared__ float lds_red[8 * 516];   // per-wave 516 floats (padded 2064B)
  const int tid = threadIdx.x;
  const int b = blockIdx.x;
  const int l = tid & 63;
  const int wv = tid >> 6;
  const int tok0 = b * 64 + wv * 8;
  const int kb = l * 4;                // lane's k offset in each 256-chunk

  // acc[t][e4] = float4 over experts e4*4..e4*4+3 (partial dots, lane's k)
  float4 acc[8][4];
#pragma unroll
  for (int t = 0; t < 8; ++t)
#pragma unroll
    for (int e4 = 0; e4 < 4; ++e4) acc[t][e4] = make_float4(0.f, 0.f, 0.f, 0.f);

#pragma unroll 2
  for (int j = 0; j < 8; ++j) {
    const float* xj = x + (size_t)tok0 * MODEL_DIM + j * 256 + kb;
    const float* wj = wg + j * 256 + kb;
    float4 xv[8];
#pragma unroll
    for (int t = 0; t < 8; ++t)
      xv[t] = *reinterpret_cast<const float4*>(xj + (size_t)t * MODEL_DIM);
    // e in two halves of 8 to bound VGPR pressure
#pragma unroll
    for (int h = 0; h < 2; ++h) {
      float4 wf[8];
#pragma unroll
      for (int e8 = 0; e8 < 8; ++e8)
        wf[e8] = *reinterpret_cast<const float4*>(wj + (h * 8 + e8) * MODEL_DIM);
#pragma unroll
      for (int t = 0; t < 8; ++t) {
#pragma unroll
        for (int p = 0; p < 2; ++p) {   // e4 = h*2+p
          acc[t][h * 2 + p].x += dot4(xv[t], wf[p * 4 + 0]);
          acc[t][h * 2 + p].y += dot4(xv[t], wf[p * 4 + 1]);
          acc[t][h * 2 + p].z += dot4(xv[t], wf[p * 4 + 2]);
          acc[t][h * 2 + p].w += dot4(xv[t], wf[p * 4 + 3]);
        }
      }
    }
  }

  // intra-16-lane butterfly sum via DPP (VALU pipe): masks {1,2,7,15}
#pragma unroll
  for (int t = 0; t < 8; ++t) {
#pragma unroll
    for (int e4 = 0; e4 < 4; ++e4) {
      DPP_ADD(acc[t][e4].x, 0xB1);  DPP_ADD(acc[t][e4].x, 0x4E);
      DPP_ADD(acc[t][e4].x, 0x141); DPP_ADD(acc[t][e4].x, 0x140);
      DPP_ADD(acc[t][e4].y, 0xB1);  DPP_ADD(acc[t][e4].y, 0x4E);
      DPP_ADD(acc[t][e4].y, 0x141); DPP_ADD(acc[t][e4].y, 0x140);
      DPP_ADD(acc[t][e4].z, 0xB1);  DPP_ADD(acc[t][e4].z, 0x4E);
      DPP_ADD(acc[t][e4].z, 0x141); DPP_ADD(acc[t][e4].z, 0x140);
      DPP_ADD(acc[t][e4].w, 0xB1);  DPP_ADD(acc[t][e4].w, 0x4E);
      DPP_ADD(acc[t][e4].w, 0x141); DPP_ADD(acc[t][e4].w, 0x140);
    }
  }

  // group leaders (l%16==0) write their 16-group partials: [val(t,e4)][g]
  const int g = l >> 4;
  float* red = lds_red + wv * 516;
  if ((l & 15) == 0) {
#pragma unroll
    for (int t = 0; t < 8; ++t)
#pragma unroll
      for (int e4 = 0; e4 < 4; ++e4)
        *reinterpret_cast<float4*>(red + (t * 4 + e4) * 16 + g * 4) = acc[t][e4];
  }
  __syncthreads();

  if (tid < 64) {   // lane = token within block
    const float* r = lds_red + (tid >> 3) * 516 + (tid & 7) * 64;
    const int t = b * 64 + tid;
    float logit[NUM_EXPERTS];
#pragma unroll
    for (int e4 = 0; e4 < 4; ++e4) {
      float4 s0 = *reinterpret_cast<const float4*>(r + e4 * 16 + 0);
      float4 s1 = *reinterpret_cast<const float4*>(r + e4 * 16 + 4);
      float4 s2 = *reinterpret_cast<const float4*>(r + e4 * 16 + 8);
      float4 s3 = *reinterpret_cast<const float4*>(r + e4 * 16 + 12);
      logit[e4 * 4 + 0] = (s0.x + s1.x) + (s2.x + s3.x);
      logit[e4 * 4 + 1] = (s0.y + s1.y) + (s2.y + s3.y);
      logit[e4 * 4 + 2] = (s0.z + s1.z) + (s2.z + s3.z);
      logit[e4 * 4 + 3] = (s0.w + s1.w) + (s2.w + s3.w);
    }

    float m = logit[0];
#pragma unroll
    for (int e = 1; e < NUM_EXPERTS; e++) m = fmaxf(m, logit[e]);
    float gg[NUM_EXPERTS]; float z = 0.f;
#pragma unroll
    for (int e = 0; e < NUM_EXPERTS; e++) { gg[e] = expf(logit[e] - m); z += gg[e]; }
    float inv = 1.f / z;
#pragma unroll
    for (int e = 0; e < NUM_EXPERTS; e++) gg[e] *= inv;

    // top-2, ties -> lower index (matches lax.top_k / argmax)
    float v1 = gg[0], v2 = -1.f; int e1 = 0, e2 = 0;
#pragma unroll
    for (int e = 1; e < NUM_EXPERTS; e++) {
      if (gg[e] > v1) { v2 = v1; e2 = e1; v1 = gg[e]; e1 = e; }
      else if (gg[e] > v2) { v2 = gg[e]; e2 = e; }
    }
    out[W_OFF + 2 * t]     = v1;
    out[W_OFF + 2 * t + 1] = v2;
    scr[SC_E01 + t] = (uint8_t)(e1 | (e2 << 4));

    // per-block routed counts (token order preserved) + argmax count
    int mycount = 0, myce = 0;
    for (int e = 0; e < NUM_EXPERTS; e++) {
      unsigned long long m1 = __ballot(e1 == e);
      unsigned long long m2 = __ballot(e2 == e);
      if (tid == e) { mycount = __popcll(m1 | m2); myce = __popcll(m1); }
    }
    if (tid < NUM_EXPERTS) {
      reinterpret_cast<uint16_t*>(scr + SC_CNT)[tid * NBLK + b] = (uint16_t)mycount;
      atomicAdd(reinterpret_cast<int*>(scr + SC_CE) + tid, myce);
    }

    // me partial: butterfly over the 64 tokens
#pragma unroll
    for (int e = 0; e < NUM_EXPERTS; e++) {
#pragma unroll
      for (int off = 1; off < 64; off <<= 1) gg[e] += __shfl_xor(gg[e], off, 64);
    }
    if (tid == 0) {
      float* mp = reinterpret_cast<float*>(scr + SC_ME);
#pragma unroll
      for (int e = 0; e < NUM_EXPERTS; e++) mp[b * NUM_EXPERTS + e] = gg[e];
    }
  }
}

// ============ K2: per-expert exclusive prefix over 256 blocks ============
__global__ __launch_bounds__(256) void k_prefix(uint8_t* __restrict__ scr) {
  const uint16_t* counts = reinterpret_cast<const uint16_t*>(scr + SC_CNT);
  uint16_t* starts = reinterpret_cast<uint16_t*>(scr + SC_START);
  __shared__ int gs[NUM_EXPERTS][16];
  __shared__ int gstart[NUM_EXPERTS][17];
  const int tid = threadIdx.x;
  const int e = tid >> 4, grp = tid & 15;
  int s = 0;
  for (int c = grp * 16; c < grp * 16 + 16; c++) s += counts[e * NBLK + c];
  gs[e][grp] = s;
  __syncthreads();
  if (tid < NUM_EXPERTS) {
    int run = 0;
    for (int g2 = 0; g2 < 16; g2++) { gstart[tid][g2] = run; run += gs[tid][g2]; }
  }
  __syncthreads();
  int run = gstart[e][grp];
  for (int c = grp * 16; c < grp * 16 + 16; c++) {
    starts[e * NBLK + c] = (uint16_t)run;
    run += counts[e * NBLK + c];
  }
}

// ============ K3: l_aux ============
__global__ __launch_bounds__(64) void k_laux(
    const uint8_t* __restrict__ scr, float* __restrict__ out) {
  const float* mepart = reinterpret_cast<const float*>(scr + SC_ME);
  const int* cecnt = reinterpret_cast<const int*>(scr + SC_CE);
  const int lane = threadIdx.x;
  float prod = 0.f;
  if (lane < NUM_EXPERTS) {
    float s = 0.f;
    for (int b = 0; b < NBLK; b++) s += mepart[b * NUM_EXPERTS + lane];
    float me = s * (1.0f / N_TOKENS);
    float ce = (float)cecnt[lane] * (1.0f / N_TOKENS);
    prod = me * ce;
  }
#pragma unroll
  for (int off = 32; off > 0; off >>= 1) prod += __shfl_xor(prod, off, 64);
  if (lane == 0) out[0] = prod * (float)NUM_EXPERTS;
}

// ============ K4: scatter token ids into capacity table ============
__global__ __launch_bounds__(64) void k_scatter(
    const uint8_t* __restrict__ scr, float* __restrict__ out) {
  const uint16_t* starts = reinterpret_cast<const uint16_t*>(scr + SC_START);
  const int c = blockIdx.x;
  const int lane = threadIdx.x;
  const int t = c * 64 + lane;
  const int v = scr[SC_E01 + t];
  const int e1 = v & 15, e2 = v >> 4;
  const unsigned long long below = (1ull << lane) - 1ull;
  int p1 = CAPACITY, p2 = CAPACITY;
  for (int e = 0; e < NUM_EXPERTS; e++) {
    unsigned long long m = __ballot(e1 == e) | __ballot(e2 == e);
    int r = __popcll(m & below);
    int sbase = (int)starts[e * NBLK + c];
    if (e1 == e) p1 = sbase + r;
    if (e2 == e) p2 = sbase + r;
  }
  float tf = (float)t;   // exact in fp32
  if ((unsigned)p1 < (unsigned)CAPACITY) out[IDX_OFF + e1 * CAPACITY + p1] = tf;
  if ((unsigned)p2 < (unsigned)CAPACITY) out[IDX_OFF + e2 * CAPACITY + p2] = tf;
}

// ============ K5: fill -1 in empty index slots ============
__global__ __launch_bounds__(256) void k_fill_idx(
    const uint8_t* __restrict__ scr, float* __restrict__ out) {
  const uint16_t* counts = reinterpret_cast<const uint16_t*>(scr + SC_CNT);
  const uint16_t* starts = reinterpret_cast<const uint16_t*>(scr + SC_START);
  const int i = blockIdx.x * 256 + threadIdx.x;   // 0..32767
  const int e = i >> 11;
  const int p = i & (CAPACITY - 1);
  const int tot = (int)starts[e * NBLK + NBLK - 1] + (int)counts[e * NBLK + NBLK - 1];
  if (p >= tot) out[IDX_OFF + i] = -1.0f;
}

// ============ K6 (LAST — clobbers scratch): expert_ids ============
__global__ __launch_bounds__(256) void k_eid(float* __restrict__ out) {
  const int i = blockIdx.x * 256 + threadIdx.x;   // 0..32767
  out[EID_OFF + i] = (float)(i >> 11);
}

extern "C" void kernel_launch(void* const* d_in, const int* in_sizes, int n_in,
                              void* d_out, int out_size, void* d_ws, size_t ws_size,
                              hipStream_t stream) {
  const float* x  = (const float*)d_in[0];
  const float* wg = (const float*)d_in[1];
  float* out = (float*)d_out;
  uint8_t* scr = (uint8_t*)d_out + SCR_BYTE;
  (void)d_ws; (void)ws_size;

  hipMemsetAsync(scr + SC_CE, 0, NUM_EXPERTS * sizeof(int), stream);
  k_gate<<<NBLK, 512, 0, stream>>>(x, wg, out, scr);
  k_prefix<<<1, 256, 0, stream>>>(scr);
  k_laux<<<1, 64, 0, stream>>>(scr, out);
  k_scatter<<<NBLK, 64, 0, stream>>>(scr, out);
  k_fill_idx<<<128, 256, 0, stream>>>(scr, out);
  k_eid<<<128, 256, 0, stream>>>(out);
}